// Round 9
// baseline (79.953 us; speedup 1.0000x reference)
//
#include <hip/hip_runtime.h>
#include <math.h>

// HybridQuanvolutionEstimator — analytic circuit collapse + bf16 MFMA linear.
//
// z0=cos(a0+th0); z1=cos(th1)*cos(a1); z2=cos(a2); z3=cos(a3+th3)
// qf[b,4p..4p+3] = [z0, z0*z1, z0*z1*z2, z1*z2*z3]
// logits = qf @ lin_w.T + lin_b ; out = log_softmax(logits)
//
// R9 vs R5/R8: x staged into LDS with dense coalesced float4 loads (each
// element read from global exactly ONCE, no TA scatter — R5 scattered 8B
// loads over 2KB spans; R8 was coalesced but read x 4x). Conv stencils then
// read from LDS (8-way bank aliasing ~2.9x on the cheap DS pipe). Extra
// barrier between x-stage and feature phase. MFMA / reduce / softmax
// unchanged from R5 (verified).

#define NB   4096
#define BPB  4
#define GRID (NB / BPB)          // 1024
#define RS   808                 // bf16 row stride; rows 16B-aligned

using short8  = __attribute__((ext_vector_type(8))) short;
using float4v = __attribute__((ext_vector_type(4))) float;

__device__ __forceinline__ unsigned short f2bf(float f) {
    unsigned u = __builtin_bit_cast(unsigned, f);
    return (unsigned short)((u + 0x7FFFu + ((u >> 16) & 1u)) >> 16);
}

__global__ __launch_bounds__(256) void hqe_kernel(
    const float* __restrict__ x,       // [B, 784]
    const float* __restrict__ conv_w,  // [4,1,2,2]
    const float* __restrict__ conv_b,  // [4]
    const float* __restrict__ q_theta, // [4]
    const float* __restrict__ lin_w,   // [10, 784]
    const float* __restrict__ lin_b,   // [10]
    float* __restrict__ out)           // [B, 10]
{
    // rows 0..3: qf (A, m=batch); rows 4..13: lin_w bf16 (B, n=output);
    // rows 14..19: allocated, read only into discarded C entries.
    __shared__ __align__(16) unsigned short lds[20 * RS];   // 32320 B
    __shared__ __align__(16) float xs[BPB * 784];           // 12544 B
    __shared__ __align__(16) float red_s[4 * 16 * 16];      // 4096 B
    __shared__ float lg_s[BPB * 10];
    __shared__ float off_s[BPB];

    const int t = threadIdx.x;
    const int b0 = blockIdx.x * BPB;

    // ---- phase A: stage x for 4 images — dense, coalesced, read-once
    {
        const float4* src = (const float4*)(x + (size_t)b0 * 784);
        float4* dst = (float4*)xs;
        for (int i = t; i < BPB * 196; i += 256) dst[i] = src[i];   // 784 f4
    }

    // ---- phase B: zero pad cols [784,808) of all 20 rows; stage lin_w
    for (int i = t; i < 20 * 12; i += 256) {
        const int r = i / 12, d = i - 12 * r;
        ((unsigned*)(lds + r * RS + 784))[d] = 0u;
    }
    {
        const float4* lw4 = (const float4*)lin_w;   // 1960 float4
        for (int i = t; i < 1960; i += 256) {
            const int o = i / 196;
            const int k0 = 4 * (i - 196 * o);
            const float4 v = lw4[i];
            const unsigned lo = f2bf(v.x) | ((unsigned)f2bf(v.y) << 16);
            const unsigned hi = f2bf(v.z) | ((unsigned)f2bf(v.w) << 16);
            *(uint2*)(lds + (4 + o) * RS + k0) = make_uint2(lo, hi);
        }
    }

    const float th0 = q_theta[0];
    const float ct1 = __cosf(q_theta[1]);
    const float th3 = q_theta[3];

    __syncthreads();   // xs written by all threads, read cross-thread below

    // ---- phase C: features; task (b,p), stencils read from LDS xs
    for (int i = t; i < BPB * 196; i += 256) {
        const int b = i / 196;
        const int p = i - 196 * b;
        const int c = p / 49;
        const int s0 = 4 * p - 196 * c;       // spatial base in 14x14
        const float4 cw = ((const float4*)conv_w)[c];
        const float cb = conv_b[c];
        const float* xb = xs + b * 784;

        float a[4];
#pragma unroll
        for (int j = 0; j < 4; ++j) {
            const int s = s0 + j;
            const int h = s / 14;
            const int w2 = s - 14 * h;
            const float* xp = xb + 56 * h + 2 * w2;
            const float2 top = *(const float2*)xp;
            const float2 bot = *(const float2*)(xp + 28);
            a[j] = cb + top.x * cw.x + top.y * cw.y + bot.x * cw.z + bot.y * cw.w;
        }
        const float z0 = __cosf(a[0] + th0);
        const float z1 = ct1 * __cosf(a[1]);
        const float z2 = __cosf(a[2]);
        const float z3 = __cosf(a[3] + th3);
        const float f1 = z0 * z1;
        const float f2 = f1 * z2;
        const float f3 = z1 * z2 * z3;
        const unsigned lo = f2bf(z0) | ((unsigned)f2bf(f1) << 16);
        const unsigned hi = f2bf(f2) | ((unsigned)f2bf(f3) << 16);
        *(uint2*)(lds + b * RS + 4 * p) = make_uint2(lo, hi);
    }

    __syncthreads();

    // ---- MFMA: K = 25 interleaved 32-tiles; wave wv takes k = 32*(wv+4*kk)
    {
        const int wv = t >> 6;
        const int lane = t & 63;
        const int mrow = lane & 15;
        const int qd = lane >> 4;
        const unsigned short* qrow = lds + mrow * RS + 8 * qd;        // A
        const unsigned short* wrow = lds + (4 + mrow) * RS + 8 * qd;  // B
        float4v acc = {0.f, 0.f, 0.f, 0.f};
#pragma unroll
        for (int kk = 0; kk < 7; ++kk) {
            const int k = 32 * (wv + 4 * kk);
            if (k < 800) {
                const short8 af = *(const short8*)(qrow + k);
                const short8 bf = *(const short8*)(wrow + k);
                acc = __builtin_amdgcn_mfma_f32_16x16x32_bf16(af, bf, acc, 0, 0, 0);
            }
        }
        // C: col = lane&15 (=n), rows = qd*4+reg (=m). Store [wv][n][m].
        *(float4v*)(red_s + (wv * 16 + mrow) * 16 + qd * 4) = acc;
    }

    __syncthreads();

    // ---- reduce 4 partial tiles; keep m<4 (batch), n<10 (outputs)
    {
        const int n = t >> 4;
        const int m = t & 15;
        if (m < BPB && n < 10) {
            const float s = red_s[0 * 256 + n * 16 + m] + red_s[1 * 256 + n * 16 + m]
                          + red_s[2 * 256 + n * 16 + m] + red_s[3 * 256 + n * 16 + m];
            lg_s[m * 10 + n] = s + lin_b[n];
        }
    }

    __syncthreads();

    if (t < BPB) {
        float mx = -INFINITY;
#pragma unroll
        for (int j = 0; j < 10; ++j) mx = fmaxf(mx, lg_s[t * 10 + j]);
        float sum = 0.0f;
#pragma unroll
        for (int j = 0; j < 10; ++j) sum += __expf(lg_s[t * 10 + j] - mx);
        off_s[t] = mx + __logf(sum);
    }

    __syncthreads();

    if (t < BPB * 10) {
        out[(size_t)b0 * 10 + t] = lg_s[t] - off_s[t / 10];
    }
}

extern "C" void kernel_launch(void* const* d_in, const int* in_sizes, int n_in,
                              void* d_out, int out_size, void* d_ws, size_t ws_size,
                              hipStream_t stream) {
    const float* x       = (const float*)d_in[0];
    const float* conv_w  = (const float*)d_in[1];
    const float* conv_b  = (const float*)d_in[2];
    const float* q_theta = (const float*)d_in[3];
    const float* lin_w   = (const float*)d_in[4];
    const float* lin_b   = (const float*)d_in[5];
    float* out = (float*)d_out;

    hqe_kernel<<<dim3(GRID), dim3(256), 0, stream>>>(x, conv_w, conv_b, q_theta,
                                                     lin_w, lin_b, out);
}

// Round 10
// 74.936 us; speedup vs baseline: 1.0670x; 1.0670x over previous
//
#include <hip/hip_runtime.h>
#include <math.h>

// HybridQuanvolutionEstimator — analytic circuit collapse + bf16 MFMA linear.
//
// z0=cos(a0+th0); z1=cos(th1)*cos(a1); z2=cos(a2); z3=cos(a3+th3)
// qf[b,4p..4p+3] = [z0, z0*z1, z0*z1*z2, z1*z2*z3]
// logits = qf @ lin_w.T + lin_b ; out = log_softmax(logits)
//
// R10 = revert to R5 (best: 74.1 µs). Tested and rejected alternatives:
//   R6 (fp16 LDS z-bounce): +9.4 µs — per-iter lgkmcnt(0) drains
//   R8 (dense mapping + DPP quad share): +2.3 µs — 4x x re-read
//   R9 (x staged in LDS): +5.9 µs — stencil bank conflicts + extra barrier
// Structure: BPB=4, grid 1024 (4 blocks/CU), fused LDS (qf rows 0..3,
// lin_w bf16 rows 4..13, RS=808), K = 25 interleaved 32-tiles over 4 waves,
// one 16x16x32 bf16 MFMA accumulator per wave, LDS tile reduce, log-softmax.

#define NB   4096
#define BPB  4
#define GRID (NB / BPB)          // 1024
#define RS   808                 // LDS row stride (bf16 elems); rows 16B-aligned

using short8  = __attribute__((ext_vector_type(8))) short;
using float4v = __attribute__((ext_vector_type(4))) float;

__device__ __forceinline__ unsigned short f2bf(float f) {
    unsigned u = __builtin_bit_cast(unsigned, f);
    return (unsigned short)((u + 0x7FFFu + ((u >> 16) & 1u)) >> 16);
}

__global__ __launch_bounds__(256) void hqe_kernel(
    const float* __restrict__ x,       // [B, 784]
    const float* __restrict__ conv_w,  // [4,1,2,2]
    const float* __restrict__ conv_b,  // [4]
    const float* __restrict__ q_theta, // [4]
    const float* __restrict__ lin_w,   // [10, 784]
    const float* __restrict__ lin_b,   // [10]
    float* __restrict__ out)           // [B, 10]
{
    // rows 0..3: qf (A, m=batch); rows 4..13: lin_w bf16 (B, n=output);
    // rows 14..19: never written, read only into discarded C entries.
    __shared__ __align__(16) unsigned short lds[20 * RS];   // 32320 B
    __shared__ __align__(16) float red_s[4 * 16 * 16];      // per-wave C tiles
    __shared__ float lg_s[BPB * 10];
    __shared__ float off_s[BPB];

    const int t = threadIdx.x;
    const int b0 = blockIdx.x * BPB;

    // ---- zero pad cols [784,808) of all 20 rows (12 dwords x 20 rows)
    for (int i = t; i < 20 * 12; i += 256) {
        const int r = i / 12, d = i - 12 * r;
        ((unsigned*)(lds + r * RS + 784))[d] = 0u;
    }

    // ---- stage lin_w -> bf16 B rows (abs rows 4..13)
    {
        const float4* lw4 = (const float4*)lin_w;   // 1960 float4
        for (int i = t; i < 1960; i += 256) {
            const int o = i / 196;
            const int k0 = 4 * (i - 196 * o);
            const float4 v = lw4[i];
            const unsigned lo = f2bf(v.x) | ((unsigned)f2bf(v.y) << 16);
            const unsigned hi = f2bf(v.z) | ((unsigned)f2bf(v.w) << 16);
            *(uint2*)(lds + (4 + o) * RS + k0) = make_uint2(lo, hi);
        }
    }

    const float th0 = q_theta[0];
    const float ct1 = __cosf(q_theta[1]);
    const float th3 = q_theta[3];

    // ---- features: task (b,p); conv read straight from global x
    for (int i = t; i < BPB * 196; i += 256) {
        const int b = i / 196;
        const int p = i - 196 * b;
        const int c = p / 49;
        const int s0 = 4 * p - 196 * c;       // spatial base in 14x14
        const float4 cw = ((const float4*)conv_w)[c];
        const float cb = conv_b[c];
        const float* xb = x + (size_t)(b0 + b) * 784;

        float a[4];
#pragma unroll
        for (int j = 0; j < 4; ++j) {
            const int s = s0 + j;
            const int h = s / 14;
            const int w2 = s - 14 * h;
            const float* xp = xb + h * 56 + 2 * w2;
            const float2 top = *(const float2*)xp;
            const float2 bot = *(const float2*)(xp + 28);
            a[j] = cb + top.x * cw.x + top.y * cw.y + bot.x * cw.z + bot.y * cw.w;
        }
        const float z0 = __cosf(a[0] + th0);
        const float z1 = ct1 * __cosf(a[1]);
        const float z2 = __cosf(a[2]);
        const float z3 = __cosf(a[3] + th3);
        const float f1 = z0 * z1;
        const float f2 = f1 * z2;
        const float f3 = z1 * z2 * z3;
        const unsigned lo = f2bf(z0) | ((unsigned)f2bf(f1) << 16);
        const unsigned hi = f2bf(f2) | ((unsigned)f2bf(f3) << 16);
        *(uint2*)(lds + b * RS + 4 * p) = make_uint2(lo, hi);
    }

    __syncthreads();

    // ---- MFMA: K = 25 interleaved 32-tiles; wave wv takes k = 32*(wv+4*kk)
    {
        const int wv = t >> 6;
        const int lane = t & 63;
        const int mrow = lane & 15;
        const int qd = lane >> 4;
        const unsigned short* qrow = lds + mrow * RS + 8 * qd;        // A
        const unsigned short* wrow = lds + (4 + mrow) * RS + 8 * qd;  // B
        float4v acc = {0.f, 0.f, 0.f, 0.f};
#pragma unroll
        for (int kk = 0; kk < 7; ++kk) {
            const int k = 32 * (wv + 4 * kk);
            if (k < 800) {
                const short8 af = *(const short8*)(qrow + k);
                const short8 bf = *(const short8*)(wrow + k);
                acc = __builtin_amdgcn_mfma_f32_16x16x32_bf16(af, bf, acc, 0, 0, 0);
            }
        }
        // C: col = lane&15 (=n), rows = qd*4+reg (=m). Store [wv][n][m].
        *(float4v*)(red_s + (wv * 16 + mrow) * 16 + qd * 4) = acc;
    }

    __syncthreads();

    // ---- reduce 4 partial tiles; keep m<4 (batch), n<10 (outputs)
    {
        const int n = t >> 4;
        const int m = t & 15;
        if (m < BPB && n < 10) {
            const float s = red_s[0 * 256 + n * 16 + m] + red_s[1 * 256 + n * 16 + m]
                          + red_s[2 * 256 + n * 16 + m] + red_s[3 * 256 + n * 16 + m];
            lg_s[m * 10 + n] = s + lin_b[n];
        }
    }

    __syncthreads();

    if (t < BPB) {
        float mx = -INFINITY;
#pragma unroll
        for (int j = 0; j < 10; ++j) mx = fmaxf(mx, lg_s[t * 10 + j]);
        float sum = 0.0f;
#pragma unroll
        for (int j = 0; j < 10; ++j) sum += __expf(lg_s[t * 10 + j] - mx);
        off_s[t] = mx + __logf(sum);
    }

    __syncthreads();

    if (t < BPB * 10) {
        out[(size_t)b0 * 10 + t] = lg_s[t] - off_s[t / 10];
    }
}

extern "C" void kernel_launch(void* const* d_in, const int* in_sizes, int n_in,
                              void* d_out, int out_size, void* d_ws, size_t ws_size,
                              hipStream_t stream) {
    const float* x       = (const float*)d_in[0];
    const float* conv_w  = (const float*)d_in[1];
    const float* conv_b  = (const float*)d_in[2];
    const float* q_theta = (const float*)d_in[3];
    const float* lin_w   = (const float*)d_in[4];
    const float* lin_b   = (const float*)d_in[5];
    float* out = (float*)d_out;

    hqe_kernel<<<dim3(GRID), dim3(256), 0, stream>>>(x, conv_w, conv_b, q_theta,
                                                     lin_w, lin_b, out);
}